// Round 6
// baseline (627.454 us; speedup 1.0000x reference)
//
#include <hip/hip_runtime.h>
#include <math.h>

#define S 2048
#define HID 1024
#define NH 16
#define HD 64
#define BH 32   // B * NH

typedef __attribute__((ext_vector_type(8))) short bf16x8;
typedef __attribute__((ext_vector_type(4))) float f32x4;
typedef __attribute__((ext_vector_type(8))) unsigned short ush8;
typedef unsigned short u16;
typedef unsigned int u32;

__device__ __forceinline__ u16 f2bf(float f) {
    unsigned u = __float_as_uint(f);
    u += 0x7fffu + ((u >> 16) & 1u);
    return (u16)(u >> 16);
}
__device__ __forceinline__ float bf2f(u16 h) {
    return __uint_as_float(((unsigned)h) << 16);
}

// ---------------------------------------------------------------------------
// Split fp32 -> (hi, lo) bf16 for X and all four weights in ONE launch.
// ---------------------------------------------------------------------------
__global__ __launch_bounds__(256)
void split_all(const float* __restrict__ X,  const float* __restrict__ Wq,
               const float* __restrict__ Wk, const float* __restrict__ Wv,
               const float* __restrict__ Wo,
               u16* __restrict__ Xh,  u16* __restrict__ Xl,
               u16* __restrict__ Wqh, u16* __restrict__ Wql,
               u16* __restrict__ Wkh, u16* __restrict__ Wkl,
               u16* __restrict__ Wvh, u16* __restrict__ Wvl,
               u16* __restrict__ Woh, u16* __restrict__ Wol)
{
    size_t i = (size_t)blockIdx.x * 256 + threadIdx.x;
    const float* s; u16* h; u16* l; size_t o;
    if (i < (size_t)(1u << 20)) { s = X; h = Xh; l = Xl; o = i; }
    else {
        size_t j = i - (1u << 20);
        int wsel = (int)(j >> 18); o = j & ((1u << 18) - 1);
        s = wsel == 0 ? Wq  : wsel == 1 ? Wk  : wsel == 2 ? Wv  : Wo;
        h = wsel == 0 ? Wqh : wsel == 1 ? Wkh : wsel == 2 ? Wvh : Woh;
        l = wsel == 0 ? Wql : wsel == 1 ? Wkl : wsel == 2 ? Wvl : Wol;
    }
    float4 v = ((const float4*)s)[o];
    ushort4 hv, lv;
#define SP(c, k) { unsigned u = __float_as_uint(v.c);                      \
                   unsigned hb = u & 0xffff0000u;                          \
                   float d = v.c - __uint_as_float(hb);                    \
                   hv.k = (u16)(u >> 16);                                  \
                   lv.k = (u16)(__float_as_uint(d) >> 16); }
    SP(x, x) SP(y, y) SP(z, z) SP(w, w)
#undef SP
    ((ushort4*)h)[o] = hv;
    ((ushort4*)l)[o] = lv;
}

// ---------------------------------------------------------------------------
// Split-precision MFMA GEMM: Y = X @ W^T + b. Output bf16 (b,h,s,d).
// grid (8, 32, 3)
// ---------------------------------------------------------------------------
__global__ __launch_bounds__(256)
void qkv_mfma(const u16* __restrict__ Xh, const u16* __restrict__ Xl,
              const u16* __restrict__ Wh_q, const u16* __restrict__ Wl_q,
              const u16* __restrict__ Wh_k, const u16* __restrict__ Wl_k,
              const u16* __restrict__ Wh_v, const u16* __restrict__ Wl_v,
              const float* __restrict__ bq_, const float* __restrict__ bk_,
              const float* __restrict__ bv_,
              u16* __restrict__ Qb, u16* __restrict__ Kb, u16* __restrict__ Vb)
{
    const int z = blockIdx.z;
    const u16* __restrict__ Wh = z == 0 ? Wh_q : (z == 1 ? Wh_k : Wh_v);
    const u16* __restrict__ Wl = z == 0 ? Wl_q : (z == 1 ? Wl_k : Wl_v);
    const float* __restrict__ bias = z == 0 ? bq_ : (z == 1 ? bk_ : bv_);
    u16* __restrict__ Ob = z == 0 ? Qb : (z == 1 ? Kb : Vb);

    __shared__ u16 Ah[128 * 40], Al[128 * 40], Bh[128 * 40], Bl[128 * 40];
    const int t = threadIdx.x;
    const int m0 = blockIdx.y * 128, n0 = blockIdx.x * 128;
    const int srow = t >> 1, scol = (t & 1) * 16;
    const int lane = t & 63, w = t >> 6, wm = w >> 1, wn = w & 1;
    const int lr = lane & 15, lg = lane >> 4;

    f32x4 acc[4][4] = {{{0.f, 0.f, 0.f, 0.f}}};
    for (int k0 = 0; k0 < HID; k0 += 32) {
        size_t ao = (size_t)(m0 + srow) * HID + k0 + scol;
        size_t bo = (size_t)(n0 + srow) * HID + k0 + scol;
        ush8 a0 = *(const ush8*)(Xh + ao), a1 = *(const ush8*)(Xh + ao + 8);
        ush8 a2 = *(const ush8*)(Xl + ao), a3 = *(const ush8*)(Xl + ao + 8);
        ush8 b0 = *(const ush8*)(Wh + bo), b1 = *(const ush8*)(Wh + bo + 8);
        ush8 b2 = *(const ush8*)(Wl + bo), b3 = *(const ush8*)(Wl + bo + 8);
        __syncthreads();
        *(ush8*)&Ah[srow * 40 + scol] = a0; *(ush8*)&Ah[srow * 40 + scol + 8] = a1;
        *(ush8*)&Al[srow * 40 + scol] = a2; *(ush8*)&Al[srow * 40 + scol + 8] = a3;
        *(ush8*)&Bh[srow * 40 + scol] = b0; *(ush8*)&Bh[srow * 40 + scol + 8] = b1;
        *(ush8*)&Bl[srow * 40 + scol] = b2; *(ush8*)&Bl[srow * 40 + scol + 8] = b3;
        __syncthreads();
        bf16x8 fbh[4], fbl[4];
#pragma unroll
        for (int ni = 0; ni < 4; ++ni) {
            fbh[ni] = *(const bf16x8*)&Bh[(wn * 64 + ni * 16 + lr) * 40 + lg * 8];
            fbl[ni] = *(const bf16x8*)&Bl[(wn * 64 + ni * 16 + lr) * 40 + lg * 8];
        }
#pragma unroll
        for (int mi = 0; mi < 4; ++mi) {
            bf16x8 fah = *(const bf16x8*)&Ah[(wm * 64 + mi * 16 + lr) * 40 + lg * 8];
            bf16x8 fal = *(const bf16x8*)&Al[(wm * 64 + mi * 16 + lr) * 40 + lg * 8];
#pragma unroll
            for (int ni = 0; ni < 4; ++ni) {
                f32x4 c = acc[mi][ni];
                c = __builtin_amdgcn_mfma_f32_16x16x32_bf16(fah, fbh[ni], c, 0, 0, 0);
                c = __builtin_amdgcn_mfma_f32_16x16x32_bf16(fah, fbl[ni], c, 0, 0, 0);
                c = __builtin_amdgcn_mfma_f32_16x16x32_bf16(fal, fbh[ni], c, 0, 0, 0);
                acc[mi][ni] = c;
            }
        }
    }
    const int hh = blockIdx.x * 2 + wn;
    float bv4[4];
#pragma unroll
    for (int ni = 0; ni < 4; ++ni) bv4[ni] = bias[n0 + wn * 64 + ni * 16 + lr];
#pragma unroll
    for (int mi = 0; mi < 4; ++mi)
#pragma unroll
        for (int r = 0; r < 4; ++r) {
            int m = m0 + wm * 64 + mi * 16 + lg * 4 + r;
            int b = m >> 11, s = m & 2047;
#pragma unroll
            for (int ni = 0; ni < 4; ++ni) {
                float v = acc[mi][ni][r] + bv4[ni];
                Ob[((size_t)(b * NH + hh) * S + s) * HD + ni * 16 + lr] = f2bf(v);
            }
        }
}

// ---------------------------------------------------------------------------
// out = OH @ Wo^T + bo (split precision, fp32 out). grid (8, 32)
// ---------------------------------------------------------------------------
__global__ __launch_bounds__(256)
void out_mfma(const u16* __restrict__ Xh, const u16* __restrict__ Xl,
              const u16* __restrict__ Wh, const u16* __restrict__ Wl,
              const float* __restrict__ bo_, float* __restrict__ Y)
{
    __shared__ u16 Ah[128 * 40], Al[128 * 40], Bh[128 * 40], Bl[128 * 40];
    const int t = threadIdx.x;
    const int m0 = blockIdx.y * 128, n0 = blockIdx.x * 128;
    const int srow = t >> 1, scol = (t & 1) * 16;
    const int lane = t & 63, w = t >> 6, wm = w >> 1, wn = w & 1;
    const int lr = lane & 15, lg = lane >> 4;

    f32x4 acc[4][4] = {{{0.f, 0.f, 0.f, 0.f}}};
    for (int k0 = 0; k0 < HID; k0 += 32) {
        size_t ao = (size_t)(m0 + srow) * HID + k0 + scol;
        size_t bo = (size_t)(n0 + srow) * HID + k0 + scol;
        ush8 a0 = *(const ush8*)(Xh + ao), a1 = *(const ush8*)(Xh + ao + 8);
        ush8 a2 = *(const ush8*)(Xl + ao), a3 = *(const ush8*)(Xl + ao + 8);
        ush8 b0 = *(const ush8*)(Wh + bo), b1 = *(const ush8*)(Wh + bo + 8);
        ush8 b2 = *(const ush8*)(Wl + bo), b3 = *(const ush8*)(Wl + bo + 8);
        __syncthreads();
        *(ush8*)&Ah[srow * 40 + scol] = a0; *(ush8*)&Ah[srow * 40 + scol + 8] = a1;
        *(ush8*)&Al[srow * 40 + scol] = a2; *(ush8*)&Al[srow * 40 + scol + 8] = a3;
        *(ush8*)&Bh[srow * 40 + scol] = b0; *(ush8*)&Bh[srow * 40 + scol + 8] = b1;
        *(ush8*)&Bl[srow * 40 + scol] = b2; *(ush8*)&Bl[srow * 40 + scol + 8] = b3;
        __syncthreads();
        bf16x8 fbh[4], fbl[4];
#pragma unroll
        for (int ni = 0; ni < 4; ++ni) {
            fbh[ni] = *(const bf16x8*)&Bh[(wn * 64 + ni * 16 + lr) * 40 + lg * 8];
            fbl[ni] = *(const bf16x8*)&Bl[(wn * 64 + ni * 16 + lr) * 40 + lg * 8];
        }
#pragma unroll
        for (int mi = 0; mi < 4; ++mi) {
            bf16x8 fah = *(const bf16x8*)&Ah[(wm * 64 + mi * 16 + lr) * 40 + lg * 8];
            bf16x8 fal = *(const bf16x8*)&Al[(wm * 64 + mi * 16 + lr) * 40 + lg * 8];
#pragma unroll
            for (int ni = 0; ni < 4; ++ni) {
                f32x4 c = acc[mi][ni];
                c = __builtin_amdgcn_mfma_f32_16x16x32_bf16(fah, fbh[ni], c, 0, 0, 0);
                c = __builtin_amdgcn_mfma_f32_16x16x32_bf16(fah, fbl[ni], c, 0, 0, 0);
                c = __builtin_amdgcn_mfma_f32_16x16x32_bf16(fal, fbh[ni], c, 0, 0, 0);
                acc[mi][ni] = c;
            }
        }
    }
    float bv4[4];
#pragma unroll
    for (int ni = 0; ni < 4; ++ni) bv4[ni] = bo_[n0 + wn * 64 + ni * 16 + lr];
#pragma unroll
    for (int mi = 0; mi < 4; ++mi)
#pragma unroll
        for (int r = 0; r < 4; ++r) {
            int m = m0 + wm * 64 + mi * 16 + lg * 4 + r;
#pragma unroll
            for (int ni = 0; ni < 4; ++ni)
                Y[(size_t)m * HID + n0 + wn * 64 + ni * 16 + lr] =
                    acc[mi][ni][r] + bv4[ni];
        }
}

// ---------------------------------------------------------------------------
// Fused attention, swapped-QK^T + k-split layout.
// Block: 512 thr = 8 waves = 4 q-groups (16 q each) x 2 k-halves (1024 k).
// grid 1024 (b,qt,h XCD-swizzled). KVBLK=32. Per lane: one q row,
// k contiguous in 4s -> int4/float4 dist/idf/mask/attn accesses.
// Pass A: online per-lane (M,S), merged via 2 shfl + LDS cross-half.
// Pass B: recompute (identical fragments), write attn fp32 once, PV MFMA;
// oacc halves merged through the dead P buffer.
// ---------------------------------------------------------------------------
__global__ __launch_bounds__(512, 8)
void attn_pv(const u16* __restrict__ Qb, const u16* __restrict__ Kb,
             const u16* __restrict__ Vb,
             const int* __restrict__ dist, const float* __restrict__ idf,
             const int* __restrict__ amask, const float* __restrict__ semb,
             const float* __restrict__ rw,
             float* __restrict__ attn, u16* __restrict__ OHh, u16* __restrict__ OHl)
{
    __shared__ u16 Ps[128 * 72];      // Q staging (rows 0..63), then P, then OA
    __shared__ u16 Ks[2][32 * 72];
    __shared__ u16 Vts[2][64 * 40];   // V^T: [d][k]
    __shared__ float SeH[51];
    __shared__ float MSm[128], MSs[128];

    const int n = blockIdx.x;
    const int xcd = n & 7, rest = n >> 3;
    const int h = rest & 15;
    const int pair = xcd * 8 + (rest >> 4);    // 0..63, shared by 16 heads
    const int b = pair >> 5, qt = pair & 31;
    const int bh = b * NH + h, q0 = qt * 64;

    const int t = threadIdx.x, lane = t & 63, w = t >> 6;
    const int wq = w & 3, wk = w >> 2;
    const int lr = lane & 15, lg = lane >> 4;
    const int q = q0 + wq * 16 + lr;           // this lane's q row

    if (t < 51) SeH[t] = semb[t * NH + h];
    {   // stage 64x64 Q tile into Ps rows 0..63
        int r = t >> 3, c = (t & 7) * 8;
        *(ush8*)&Ps[r * 72 + c] = *(const ush8*)(Qb + ((size_t)bh * S + q0 + r) * HD + c);
    }
    __syncthreads();

    bf16x8 qa0 = *(const bf16x8*)&Ps[(wq * 16 + lr) * 72 + lg * 8];
    bf16x8 qa1 = *(const bf16x8*)&Ps[(wq * 16 + lr) * 72 + 32 + lg * 8];

    const float rwv = rw[0];
    const float idq = idf[b * S + q];
    const int* dptr = dist + (size_t)(b * S + q) * S;
    const size_t kbase = (size_t)bh * S;
    const int srow = (t & 255) >> 3, scol = (t & 7) * 8, shalf = t >> 8;
    const int vr = (t & 255) & 31, vd = ((t & 255) >> 5) * 8;

    // ---------------- pass A: online row stats ----------------
    float M = -INFINITY, Ssum = 0.f;

    for (int it = 0; it < 32; ++it) {
        const int k0  = wk * 1024 + it * 32;
        const int k0s = shalf * 1024 + it * 32;
        __syncthreads();
        *(ush8*)&Ks[shalf][srow * 72 + scol] =
            *(const ush8*)(Kb + (kbase + k0s + srow) * HD + scol);
        __syncthreads();

        f32x4 c2[2];
        __builtin_amdgcn_s_setprio(1);
#pragma unroll
        for (int ni = 0; ni < 2; ++ni) {
            bf16x8 kf0 = *(const bf16x8*)&Ks[wk][(ni * 16 + lr) * 72 + lg * 8];
            bf16x8 kf1 = *(const bf16x8*)&Ks[wk][(ni * 16 + lr) * 72 + 32 + lg * 8];
            f32x4 c = {0.f, 0.f, 0.f, 0.f};
            c = __builtin_amdgcn_mfma_f32_16x16x32_bf16(kf0, qa0, c, 0, 0, 0);
            c = __builtin_amdgcn_mfma_f32_16x16x32_bf16(kf1, qa1, c, 0, 0, 0);
            c2[ni] = c;
        }
        __builtin_amdgcn_s_setprio(0);

        float sc[2][4];
        float chm = -INFINITY;
#pragma unroll
        for (int ni = 0; ni < 2; ++ni) {
            const int kb = k0 + ni * 16 + lg * 4;
            int4   dv = *(const int4*)(dptr + kb);
            float4 ik = *(const float4*)(idf + b * S + kb);
            int4   mv = *(const int4*)(amask + b * S + kb);
            int   dd[4] = {dv.x, dv.y, dv.z, dv.w};
            float ikf[4] = {ik.x, ik.y, ik.z, ik.w};
            int   mm[4] = {mv.x, mv.y, mv.z, mv.w};
#pragma unroll
            for (int r = 0; r < 4; ++r) {
                int dc = dd[r]; dc = dc < 0 ? 0 : (dc > 50 ? 50 : dc);
                float v = c2[ni][r] * 0.125f + SeH[dc] + rwv * (idq + ikf[r]);
                if (mm[r] == 0) v = -INFINITY;
                sc[ni][r] = v;
                chm = fmaxf(chm, v);
            }
        }
        if (chm > -INFINITY) {
            float mn = fmaxf(M, chm);
            float s = 0.f;
#pragma unroll
            for (int ni = 0; ni < 2; ++ni)
#pragma unroll
                for (int r = 0; r < 4; ++r) s += __expf(sc[ni][r] - mn);
            Ssum = Ssum * __expf(M - mn) + s;
            M = mn;
        }
    }
    // merge the 4 lg-lanes of this q row
#pragma unroll
    for (int off = 16; off <= 32; off <<= 1) {
        float Mo = __shfl_xor(M, off), So = __shfl_xor(Ssum, off);
        float mn = fmaxf(M, Mo);
        Ssum = Ssum * __expf(M - mn) + So * __expf(Mo - mn);
        M = mn;
    }
    // merge the two k-halves via LDS
    if (lg == 0) { MSm[w * 16 + lr] = M; MSs[w * 16 + lr] = Ssum; }
    __syncthreads();
    {
        int pw = (w + 4) & 7;
        float Mo = MSm[pw * 16 + lr], So = MSs[pw * 16 + lr];
        float mn = fmaxf(M, Mo);
        Ssum = Ssum * __expf(M - mn) + So * __expf(Mo - mn);
        M = mn;
    }
    const float Iv = 1.0f / Ssum;

    // ---------------- pass B: recompute, write attn, PV ----------------
    float* aptr = attn + (kbase + q) * S;
    f32x4 oacc[4] = {{0.f,0.f,0.f,0.f},{0.f,0.f,0.f,0.f},
                     {0.f,0.f,0.f,0.f},{0.f,0.f,0.f,0.f}};

    for (int it = 0; it < 32; ++it) {
        const int k0  = wk * 1024 + it * 32;
        const int k0s = shalf * 1024 + it * 32;
        __syncthreads();
        *(ush8*)&Ks[shalf][srow * 72 + scol] =
            *(const ush8*)(Kb + (kbase + k0s + srow) * HD + scol);
        {
            ush8 v0 = *(const ush8*)(Vb + (kbase + k0s + vr) * HD + vd);
#pragma unroll
            for (int j = 0; j < 8; ++j)
                Vts[shalf][(vd + j) * 40 + vr] = v0[j];
        }
        __syncthreads();

        f32x4 c2[2];
        __builtin_amdgcn_s_setprio(1);
#pragma unroll
        for (int ni = 0; ni < 2; ++ni) {
            bf16x8 kf0 = *(const bf16x8*)&Ks[wk][(ni * 16 + lr) * 72 + lg * 8];
            bf16x8 kf1 = *(const bf16x8*)&Ks[wk][(ni * 16 + lr) * 72 + 32 + lg * 8];
            f32x4 c = {0.f, 0.f, 0.f, 0.f};
            c = __builtin_amdgcn_mfma_f32_16x16x32_bf16(kf0, qa0, c, 0, 0, 0);
            c = __builtin_amdgcn_mfma_f32_16x16x32_bf16(kf1, qa1, c, 0, 0, 0);
            c2[ni] = c;
        }
        __builtin_amdgcn_s_setprio(0);

#pragma unroll
        for (int ni = 0; ni < 2; ++ni) {
            const int kb = k0 + ni * 16 + lg * 4;
            int4   dv = *(const int4*)(dptr + kb);
            float4 ik = *(const float4*)(idf + b * S + kb);
            int4   mv = *(const int4*)(amask + b * S + kb);
            int   dd[4] = {dv.x, dv.y, dv.z, dv.w};
            float ikf[4] = {ik.x, ik.y, ik.z, ik.w};
            int   mm[4] = {mv.x, mv.y, mv.z, mv.w};
            float pp[4];
#pragma unroll
            for (int r = 0; r < 4; ++r) {
                int dc = dd[r]; dc = dc < 0 ? 0 : (dc > 50 ? 50 : dc);
                float v = c2[ni][r] * 0.125f + SeH[dc] + rwv * (idq + ikf[r]);
                if (mm[r] == 0) v = -INFINITY;
                pp[r] = __expf(v - M) * Iv;
            }
            float4 st = make_float4(pp[0], pp[1], pp[2], pp[3]);
            *(float4*)(aptr + kb) = st;
            uint2 pk;
            pk.x = (u32)f2bf(pp[0]) | ((u32)f2bf(pp[1]) << 16);
            pk.y = (u32)f2bf(pp[2]) | ((u32)f2bf(pp[3]) << 16);
            *(uint2*)&Ps[(w * 16 + lr) * 72 + ni * 16 + lg * 4] = pk;
        }
        // PV: wave-local P rows (written by this wave above; LDS in-order)
        bf16x8 pa = *(const bf16x8*)&Ps[(w * 16 + lr) * 72 + lg * 8];
        __builtin_amdgcn_s_setprio(1);
#pragma unroll
        for (int ni = 0; ni < 4; ++ni) {
            bf16x8 vb = *(const bf16x8*)&Vts[wk][(ni * 16 + lr) * 40 + lg * 8];
            oacc[ni] = __builtin_amdgcn_mfma_f32_16x16x32_bf16(pa, vb, oacc[ni], 0, 0, 0);
        }
        __builtin_amdgcn_s_setprio(0);
    }

    // merge the two k-halves' PV partials through the dead P buffer
    __syncthreads();
    if (wk == 1) {
        float* OA = (float*)Ps;
#pragma unroll
        for (int ni = 0; ni < 4; ++ni)
#pragma unroll
            for (int r = 0; r < 4; ++r)
                OA[(wq * 16 + lg * 4 + r) * 64 + ni * 16 + lr] = oacc[ni][r];
    }
    __syncthreads();
    if (wk == 0) {
        const float* OA = (const float*)Ps;
#pragma unroll
        for (int ni = 0; ni < 4; ++ni)
#pragma unroll
            for (int r = 0; r < 4; ++r) {
                float v = oacc[ni][r] + OA[(wq * 16 + lg * 4 + r) * 64 + ni * 16 + lr];
                u16 hi = f2bf(v);
                u16 lo = f2bf(v - bf2f(hi));
                int qq = q0 + wq * 16 + lg * 4 + r;
                size_t off = ((size_t)b * S + qq) * HID + h * HD + ni * 16 + lr;
                OHh[off] = hi;
                OHl[off] = lo;
            }
    }
}

// ---------------------------------------------------------------------------
extern "C" void kernel_launch(void* const* d_in, const int* in_sizes, int n_in,
                              void* d_out, int out_size, void* d_ws, size_t ws_size,
                              hipStream_t stream)
{
    const float* hs   = (const float*)d_in[0];
    const int*   dist = (const int*)d_in[1];
    const float* idf  = (const float*)d_in[2];
    const int*   am   = (const int*)d_in[3];
    const float* Wq   = (const float*)d_in[4];
    const float* bq   = (const float*)d_in[5];
    const float* Wk   = (const float*)d_in[6];
    const float* bk   = (const float*)d_in[7];
    const float* Wv   = (const float*)d_in[8];
    const float* bv   = (const float*)d_in[9];
    const float* Wo   = (const float*)d_in[10];
    const float* bo   = (const float*)d_in[11];
    const float* se   = (const float*)d_in[12];
    const float* rw   = (const float*)d_in[13];

    float* out  = (float*)d_out;
    float* attn = out + (size_t)2 * S * HID;

    // X hi/lo hide in the (not yet written) attn output region
    u16* Xh = (u16*)attn;
    u16* Xl = Xh + (size_t)4096 * 1024;

    // workspace layout
    u16* Qb  = (u16*)d_ws;
    u16* Kb  = Qb  + (size_t)BH * S * HD;
    u16* Vb  = Kb  + (size_t)BH * S * HD;
    u16* OHh = Vb  + (size_t)BH * S * HD;
    u16* OHl = OHh + (size_t)4096 * 1024;
    u16* Woh = OHl + (size_t)4096 * 1024;
    u16* Wol = Woh + (size_t)1024 * 1024;
    u16* Wqh = Wol + (size_t)1024 * 1024;
    u16* Wql = Wqh + (size_t)1024 * 1024;
    u16* Wkh = Wql + (size_t)1024 * 1024;
    u16* Wkl = Wkh + (size_t)1024 * 1024;
    u16* Wvh = Wkl + (size_t)1024 * 1024;
    u16* Wvl = Wvh + (size_t)1024 * 1024;

    dim3 blk(256);
    split_all<<<dim3(8192), blk, 0, stream>>>(hs, Wq, Wk, Wv, Wo,
                                              Xh, Xl, Wqh, Wql, Wkh, Wkl,
                                              Wvh, Wvl, Woh, Wol);
    qkv_mfma<<<dim3(8, 32, 3), blk, 0, stream>>>(Xh, Xl, Wqh, Wql, Wkh, Wkl,
                                                 Wvh, Wvl, bq, bk, bv, Qb, Kb, Vb);
    attn_pv<<<dim3(1024), dim3(512), 0, stream>>>(Qb, Kb, Vb, dist, idf, am, se, rw,
                                                  attn, OHh, OHl);
    out_mfma<<<dim3(8, 32), blk, 0, stream>>>(OHh, OHl, Woh, Wol, bo, out);
}